// Round 1
// baseline (1109.609 us; speedup 1.0000x reference)
//
#include <hip/hip_runtime.h>
#include <math.h>

#define G    64
#define NPG  2048
#define NTOT (G * NPG)          // 131072
#define NE   (NTOT * 8)         // 1048576
#define KSEL 410
#define NK   (G * KSEL)         // 26240
#define NH   3
#define NC   20
#define HC   60

__device__ inline float leaky(float x) { return x >= 0.f ? x : 0.2f * x; }

__device__ inline void atomicMaxF(float* addr, float val) {
    float old = *addr;
    while (old < val) {
        int assumed = __float_as_int(old);
        int prev = atomicCAS((int*)addr, assumed, __float_as_int(val));
        if (prev == assumed) break;
        old = __int_as_float(prev);
    }
}

__global__ __launch_bounds__(256) void k_deg(const int* __restrict__ dst, float* __restrict__ deg) {
    int e = blockIdx.x * blockDim.x + threadIdx.x;
    if (e < NE) atomicAdd(&deg[dst[e]], 1.0f);
}

__global__ __launch_bounds__(256) void k_dinv(const float* __restrict__ deg, float* __restrict__ dinv) {
    int i = blockIdx.x * blockDim.x + threadIdx.x;
    if (i < NTOT) dinv[i] = 1.0f / sqrtf(deg[i] + 1.0f);
}

// h1 = x @ W1   (NTOT x 5) @ (5 x 10)
__global__ __launch_bounds__(256) void k_h1(const float* __restrict__ x, const float* __restrict__ W1,
                                            float* __restrict__ h1) {
    int i = blockIdx.x * blockDim.x + threadIdx.x;
    if (i >= NTOT) return;
    float xi[5];
#pragma unroll
    for (int k = 0; k < 5; k++) xi[k] = x[i * 5 + k];
#pragma unroll
    for (int j = 0; j < 10; j++) {
        float s = 0.f;
#pragma unroll
        for (int k = 0; k < 5; k++) s += xi[k] * W1[k * 10 + j];
        h1[i * 10 + j] = s;
    }
}

// agg[dst] += h[src] * dinv[src]*dinv[dst]   (nch channels)
__global__ __launch_bounds__(256) void k_edge_gcn10(const int* __restrict__ src, const int* __restrict__ dst,
                                                    const float* __restrict__ dinv, const float* __restrict__ h,
                                                    float* __restrict__ agg) {
    int e = blockIdx.x * blockDim.x + threadIdx.x;
    if (e >= NE) return;
    int s = src[e], d = dst[e];
    float c = dinv[s] * dinv[d];
#pragma unroll
    for (int j = 0; j < 10; j++) atomicAdd(&agg[d * 10 + j], h[s * 10 + j] * c);
}

__global__ __launch_bounds__(256) void k_edge_gcn1(const int* __restrict__ src, const int* __restrict__ dst,
                                                   const float* __restrict__ dinv, const float* __restrict__ h,
                                                   float* __restrict__ agg) {
    int e = blockIdx.x * blockDim.x + threadIdx.x;
    if (e >= NE) return;
    int s = src[e], d = dst[e];
    float c = dinv[s] * dinv[d];
    atomicAdd(&agg[d], h[s] * c);
}

// finalize x1 = agg + h1*dinv^2 + b1  (in place on agg); hs = x1 @ Ws
__global__ __launch_bounds__(256) void k_fin1(float* __restrict__ x1, const float* __restrict__ h1,
                                              const float* __restrict__ dinv, const float* __restrict__ b1,
                                              const float* __restrict__ Ws, float* __restrict__ hs) {
    int i = blockIdx.x * blockDim.x + threadIdx.x;
    if (i >= NTOT) return;
    float d2 = dinv[i] * dinv[i];
    float acc = 0.f;
#pragma unroll
    for (int j = 0; j < 10; j++) {
        float v = x1[i * 10 + j] + h1[i * 10 + j] * d2 + b1[j];
        x1[i * 10 + j] = v;
        acc += v * Ws[j];
    }
    hs[i] = acc;
}

__global__ __launch_bounds__(256) void k_fin_s(float* __restrict__ sagg, const float* __restrict__ hs,
                                               const float* __restrict__ dinv, const float* __restrict__ bs) {
    int i = blockIdx.x * blockDim.x + threadIdx.x;
    if (i >= NTOT) return;
    sagg[i] = sagg[i] + hs[i] * dinv[i] * dinv[i] + bs[0];
}

// per-graph top-K via bitonic sort in LDS (2048 keys). Descending; ties -> lower idx first.
__global__ __launch_bounds__(256) void k_topk(const float* __restrict__ score, int* __restrict__ perm,
                                              int* __restrict__ newidx) {
    __shared__ float sk[NPG];
    __shared__ int si[NPG];
    int g = blockIdx.x, tid = threadIdx.x;
    for (int i = tid; i < NPG; i += 256) { sk[i] = score[g * NPG + i]; si[i] = i; }
    __syncthreads();
    for (int k = 2; k <= NPG; k <<= 1) {
        for (int j = k >> 1; j > 0; j >>= 1) {
            for (int i = tid; i < NPG; i += 256) {
                int ixj = i ^ j;
                if (ixj > i) {
                    float a = sk[i], b = sk[ixj];
                    int ia = si[i], ib = si[ixj];
                    // "later in desired (descending) order" for element at i vs ixj
                    bool later_i = (a < b) || (a == b && ia > ib);
                    bool up = ((i & k) == 0);
                    if (later_i == up) { sk[i] = b; sk[ixj] = a; si[i] = ib; si[ixj] = ia; }
                }
            }
            __syncthreads();
        }
    }
    for (int r = tid; r < KSEL; r += 256) {
        int gid = g * NPG + si[r];
        int p = g * KSEL + r;
        perm[p] = gid;
        newidx[gid] = p;
    }
}

__global__ __launch_bounds__(256) void k_xp(const int* __restrict__ perm, const float* __restrict__ x1,
                                            const float* __restrict__ score, float* __restrict__ xp) {
    int p = blockIdx.x * blockDim.x + threadIdx.x;
    if (p >= NK) return;
    int gid = perm[p];
    float t = tanhf(score[gid]);
#pragma unroll
    for (int j = 0; j < 10; j++) xp[p * 10 + j] = x1[gid * 10 + j] * t;
}

// h = xp @ Wg ; al_s/al_d ; mx init with self-loop logit
__global__ __launch_bounds__(256) void k_gatfeat(const float* __restrict__ xp, const float* __restrict__ Wg,
                                                 const float* __restrict__ a_src, const float* __restrict__ a_dst,
                                                 float* __restrict__ hfeat, float* __restrict__ als,
                                                 float* __restrict__ ald, float* __restrict__ mx) {
    int p = blockIdx.x * blockDim.x + threadIdx.x;
    if (p >= NK) return;
    float xi[10];
#pragma unroll
    for (int k = 0; k < 10; k++) xi[k] = xp[p * 10 + k];
    for (int hh = 0; hh < NH; hh++) {
        float as_ = 0.f, ad_ = 0.f;
#pragma unroll
        for (int c = 0; c < NC; c++) {
            int j = hh * NC + c;
            float v = 0.f;
#pragma unroll
            for (int k = 0; k < 10; k++) v += xi[k] * Wg[k * HC + j];
            hfeat[p * HC + j] = v;
            as_ += v * a_src[j];
            ad_ += v * a_dst[j];
        }
        als[p * NH + hh] = as_;
        ald[p * NH + hh] = ad_;
        mx[p * NH + hh] = leaky(as_ + ad_);
    }
}

__global__ __launch_bounds__(256) void k_edge_max(const int* __restrict__ src, const int* __restrict__ dst,
                                                  const int* __restrict__ newidx, const float* __restrict__ als,
                                                  const float* __restrict__ ald, float* __restrict__ mx) {
    int e = blockIdx.x * blockDim.x + threadIdx.x;
    if (e >= NE) return;
    int s2 = newidx[src[e]], d2 = newidx[dst[e]];
    if (s2 < 0 || d2 < 0) return;
#pragma unroll
    for (int hh = 0; hh < NH; hh++)
        atomicMaxF(&mx[d2 * NH + hh], leaky(als[s2 * NH + hh] + ald[d2 * NH + hh]));
}

// init denom/numer with self-loop contribution
__global__ __launch_bounds__(256) void k_self(const float* __restrict__ als, const float* __restrict__ ald,
                                              const float* __restrict__ mx, const float* __restrict__ hfeat,
                                              float* __restrict__ denom, float* __restrict__ numer) {
    int p = blockIdx.x * blockDim.x + threadIdx.x;
    if (p >= NK) return;
    for (int hh = 0; hh < NH; hh++) {
        float w = expf(leaky(als[p * NH + hh] + ald[p * NH + hh]) - mx[p * NH + hh]);
        denom[p * NH + hh] = w;
#pragma unroll
        for (int c = 0; c < NC; c++)
            numer[p * HC + hh * NC + c] = hfeat[p * HC + hh * NC + c] * w;
    }
}

__global__ __launch_bounds__(256) void k_edge_sum(const int* __restrict__ src, const int* __restrict__ dst,
                                                  const int* __restrict__ newidx, const float* __restrict__ als,
                                                  const float* __restrict__ ald, const float* __restrict__ mx,
                                                  const float* __restrict__ hfeat, float* __restrict__ denom,
                                                  float* __restrict__ numer) {
    int e = blockIdx.x * blockDim.x + threadIdx.x;
    if (e >= NE) return;
    int s2 = newidx[src[e]], d2 = newidx[dst[e]];
    if (s2 < 0 || d2 < 0) return;
    for (int hh = 0; hh < NH; hh++) {
        float w = expf(leaky(als[s2 * NH + hh] + ald[d2 * NH + hh]) - mx[d2 * NH + hh]);
        atomicAdd(&denom[d2 * NH + hh], w);
#pragma unroll
        for (int c = 0; c < NC; c++)
            atomicAdd(&numer[d2 * HC + hh * NC + c], hfeat[s2 * HC + hh * NC + c] * w);
    }
}

// per-graph readout: gout[g][j] = sum_r numer/denom + bg   (block per graph, thread per column)
__global__ __launch_bounds__(64) void k_readout(const float* __restrict__ numer, const float* __restrict__ denom,
                                                const float* __restrict__ bg, float* __restrict__ gout) {
    int g = blockIdx.x, j = threadIdx.x;
    if (j >= HC) return;
    int hh = j / NC;
    float acc = 0.f;
    int base = g * KSEL;
    for (int r = 0; r < KSEL; r++) {
        int p = base + r;
        acc += numer[p * HC + j] / denom[p * NH + hh] + bg[j];
    }
    gout[g * HC + j] = acc;
}

// final MLP + log_softmax, one thread per graph
__global__ __launch_bounds__(64) void k_mlp(const float* __restrict__ gout, const float* __restrict__ Wf1,
                                            const float* __restrict__ bf1, const float* __restrict__ Wf2,
                                            const float* __restrict__ bf2, float* __restrict__ out) {
    int g = threadIdx.x;
    if (g >= G) return;
    float gi[HC];
#pragma unroll
    for (int k = 0; k < HC; k++) gi[k] = gout[g * HC + k];
    float hid[30];
    for (int j = 0; j < 30; j++) {
        float s = bf1[j];
        for (int k = 0; k < HC; k++) s += gi[k] * Wf1[k * 30 + j];
        hid[j] = s > 0.f ? s : 0.f;
    }
    float z[3];
    for (int j = 0; j < 3; j++) {
        float s = bf2[j];
        for (int k = 0; k < 30; k++) s += hid[k] * Wf2[k * 3 + j];
        z[j] = s;
    }
    float m = fmaxf(z[0], fmaxf(z[1], z[2]));
    float lse = logf(expf(z[0] - m) + expf(z[1] - m) + expf(z[2] - m)) + m;
    for (int j = 0; j < 3; j++) out[g * 3 + j] = z[j] - lse;
}

extern "C" void kernel_launch(void* const* d_in, const int* in_sizes, int n_in,
                              void* d_out, int out_size, void* d_ws, size_t ws_size,
                              hipStream_t stream) {
    const float* x     = (const float*)d_in[0];
    const int*   src   = (const int*)d_in[1];
    const int*   dst   = (const int*)d_in[2];
    // d_in[3] batch unused (derivable)
    const float* W1    = (const float*)d_in[4];
    const float* b1    = (const float*)d_in[5];
    const float* Ws    = (const float*)d_in[6];
    const float* bs    = (const float*)d_in[7];
    const float* Wg    = (const float*)d_in[8];
    const float* a_src = (const float*)d_in[9];
    const float* a_dst = (const float*)d_in[10];
    const float* bg    = (const float*)d_in[11];
    const float* Wf1   = (const float*)d_in[12];
    const float* bf1   = (const float*)d_in[13];
    const float* Wf2   = (const float*)d_in[14];
    const float* bf2   = (const float*)d_in[15];
    float* out = (float*)d_out;

    float* ws = (float*)d_ws;
    float* deg    = ws;                    // NTOT
    float* dinv   = deg + NTOT;            // NTOT
    float* h1     = dinv + NTOT;           // NTOT*10
    float* x1     = h1 + (size_t)NTOT * 10;// NTOT*10 (agg -> x1 in place)
    float* hs     = x1 + (size_t)NTOT * 10;// NTOT
    float* sagg   = hs + NTOT;             // NTOT (agg -> score)
    int*   newidx = (int*)(sagg + NTOT);   // NTOT
    int*   perm   = newidx + NTOT;         // NK
    float* xp     = (float*)(perm + NK);   // NK*10
    float* hfeat  = xp + (size_t)NK * 10;  // NK*60
    float* als    = hfeat + (size_t)NK * HC; // NK*3
    float* ald    = als + (size_t)NK * NH;
    float* mx     = ald + (size_t)NK * NH;
    float* denom  = mx + (size_t)NK * NH;
    float* numer  = denom + (size_t)NK * NH; // NK*60
    float* gout   = numer + (size_t)NK * HC; // G*60

    hipMemsetAsync(deg, 0, (size_t)NTOT * sizeof(float), stream);
    hipMemsetAsync(x1, 0, (size_t)NTOT * 10 * sizeof(float), stream);
    hipMemsetAsync(sagg, 0, (size_t)NTOT * sizeof(float), stream);
    hipMemsetAsync(newidx, 0xFF, (size_t)NTOT * sizeof(int), stream);

    k_deg<<<NE / 256, 256, 0, stream>>>(dst, deg);
    k_dinv<<<NTOT / 256, 256, 0, stream>>>(deg, dinv);
    k_h1<<<NTOT / 256, 256, 0, stream>>>(x, W1, h1);
    k_edge_gcn10<<<NE / 256, 256, 0, stream>>>(src, dst, dinv, h1, x1);
    k_fin1<<<NTOT / 256, 256, 0, stream>>>(x1, h1, dinv, b1, Ws, hs);
    k_edge_gcn1<<<NE / 256, 256, 0, stream>>>(src, dst, dinv, hs, sagg);
    k_fin_s<<<NTOT / 256, 256, 0, stream>>>(sagg, hs, dinv, bs);
    k_topk<<<G, 256, 0, stream>>>(sagg, perm, newidx);
    k_xp<<<(NK + 255) / 256, 256, 0, stream>>>(perm, x1, sagg, xp);
    k_gatfeat<<<(NK + 255) / 256, 256, 0, stream>>>(xp, Wg, a_src, a_dst, hfeat, als, ald, mx);
    k_edge_max<<<NE / 256, 256, 0, stream>>>(src, dst, newidx, als, ald, mx);
    k_self<<<(NK + 255) / 256, 256, 0, stream>>>(als, ald, mx, hfeat, denom, numer);
    k_edge_sum<<<NE / 256, 256, 0, stream>>>(src, dst, newidx, als, ald, mx, hfeat, denom, numer);
    k_readout<<<G, 64, 0, stream>>>(numer, denom, bg, gout);
    k_mlp<<<1, 64, 0, stream>>>(gout, Wf1, bf1, Wf2, bf2, out);
}

// Round 2
// 311.601 us; speedup vs baseline: 3.5610x; 3.5610x over previous
//
#include <hip/hip_runtime.h>
#include <math.h>

#define G    64
#define NPG  2048
#define NTOT (G * NPG)          // 131072
#define EPG  (NPG * 8)          // 16384 edges per graph (contiguous by construction)
#define NE   (NTOT * 8)         // 1048576
#define KSEL 410
#define NK   (G * KSEL)         // 26240
#define NH   3
#define NC   20
#define HC   60

__device__ inline float leaky(float x) { return x >= 0.f ? x : 0.2f * x; }

// h1 = x @ W1   (NTOT x 5) @ (5 x 10)
__global__ __launch_bounds__(256) void k_h1(const float* __restrict__ x, const float* __restrict__ W1,
                                            float* __restrict__ h1) {
    int i = blockIdx.x * blockDim.x + threadIdx.x;
    if (i >= NTOT) return;
    float xi[5];
#pragma unroll
    for (int k = 0; k < 5; k++) xi[k] = x[i * 5 + k];
#pragma unroll
    for (int j = 0; j < 10; j++) {
        float s = 0.f;
#pragma unroll
        for (int k = 0; k < 5; k++) s += xi[k] * W1[k * 10 + j];
        h1[i * 10 + j] = s;
    }
}

// Per-graph dst-CSR build: LDS histogram -> scan -> scatter. Also emits dinv.
__global__ __launch_bounds__(256) void k_csr(const int* __restrict__ src, const int* __restrict__ dst,
                                             float* __restrict__ dinv, int* __restrict__ rowptr,
                                             int* __restrict__ rowcnt, int* __restrict__ csr_src) {
    __shared__ int hist[NPG];
    __shared__ int rs[NPG];
    __shared__ int tsum[256];
    int g = blockIdx.x, tid = threadIdx.x;
    int nbase = g * NPG, ebase = g * EPG;
    for (int i = tid; i < NPG; i += 256) hist[i] = 0;
    __syncthreads();
    for (int e = tid; e < EPG; e += 256)
        atomicAdd(&hist[dst[ebase + e] - nbase], 1);
    __syncthreads();
    // exclusive scan of hist[0..2047] into rs
    int loc[8];
    int s = 0;
    int b8 = tid * 8;
#pragma unroll
    for (int k = 0; k < 8; k++) { loc[k] = s; s += hist[b8 + k]; }
    tsum[tid] = s;
    __syncthreads();
    for (int off = 1; off < 256; off <<= 1) {
        int v = (tid >= off) ? tsum[tid - off] : 0;
        __syncthreads();
        tsum[tid] += v;
        __syncthreads();
    }
    int off0 = tsum[tid] - s;
#pragma unroll
    for (int k = 0; k < 8; k++) rs[b8 + k] = off0 + loc[k];
    __syncthreads();
    for (int i = tid; i < NPG; i += 256) {
        int c = hist[i];
        rowcnt[nbase + i] = c;
        rowptr[nbase + i] = ebase + rs[i];
        dinv[nbase + i] = rsqrtf((float)c + 1.0f);
        hist[i] = 0;                       // becomes cursor
    }
    __syncthreads();
    for (int e = tid; e < EPG; e += 256) {
        int ee = ebase + e;
        int sv = src[ee];
        int dl = dst[ee] - nbase;
        int pos = ebase + rs[dl] + atomicAdd(&hist[dl], 1);
        csr_src[pos] = sv;
    }
}

// Gather GCN (10ch) + finalize + scorer projection, no atomics.
__global__ __launch_bounds__(256) void k_gcn10(const float* __restrict__ h1, const float* __restrict__ dinv,
                                               const int* __restrict__ rowptr, const int* __restrict__ rowcnt,
                                               const int* __restrict__ csr_src, const float* __restrict__ b1,
                                               const float* __restrict__ Ws, float* __restrict__ x1,
                                               float* __restrict__ hs) {
    int i = blockIdx.x * blockDim.x + threadIdx.x;
    if (i >= NTOT) return;
    float di = dinv[i];
    float acc[10];
#pragma unroll
    for (int j = 0; j < 10; j++) acc[j] = 0.f;
    int p0 = rowptr[i], cnt = rowcnt[i];
    for (int e = p0; e < p0 + cnt; e++) {
        int s = csr_src[e];
        float c = dinv[s] * di;
        const float* hp = h1 + (size_t)s * 10;
#pragma unroll
        for (int j = 0; j < 10; j++) acc[j] += hp[j] * c;
    }
    float d2 = di * di;
    float dot = 0.f;
#pragma unroll
    for (int j = 0; j < 10; j++) {
        float v = acc[j] + h1[(size_t)i * 10 + j] * d2 + b1[j];
        x1[(size_t)i * 10 + j] = v;
        dot += v * Ws[j];
    }
    hs[i] = dot;
}

// Gather GCN (scorer, 1ch): score[i] = di*sum(dinv[s]*hs[s]) + hs[i]*di^2 + bs
__global__ __launch_bounds__(256) void k_score(const float* __restrict__ hs, const float* __restrict__ dinv,
                                               const int* __restrict__ rowptr, const int* __restrict__ rowcnt,
                                               const int* __restrict__ csr_src, const float* __restrict__ bs,
                                               float* __restrict__ score) {
    int i = blockIdx.x * blockDim.x + threadIdx.x;
    if (i >= NTOT) return;
    float di = dinv[i];
    int p0 = rowptr[i], cnt = rowcnt[i];
    float a = 0.f;
    for (int e = p0; e < p0 + cnt; e++) {
        int s = csr_src[e];
        a += dinv[s] * hs[s];
    }
    score[i] = di * a + hs[i] * di * di + bs[0];
}

// per-graph top-K via bitonic sort in LDS (2048 keys). Descending; ties -> lower idx first.
__global__ __launch_bounds__(256) void k_topk(const float* __restrict__ score, int* __restrict__ perm,
                                              int* __restrict__ newidx) {
    __shared__ float sk[NPG];
    __shared__ int si[NPG];
    int g = blockIdx.x, tid = threadIdx.x;
    for (int i = tid; i < NPG; i += 256) { sk[i] = score[g * NPG + i]; si[i] = i; }
    __syncthreads();
    for (int k = 2; k <= NPG; k <<= 1) {
        for (int j = k >> 1; j > 0; j >>= 1) {
            for (int i = tid; i < NPG; i += 256) {
                int ixj = i ^ j;
                if (ixj > i) {
                    float a = sk[i], b = sk[ixj];
                    int ia = si[i], ib = si[ixj];
                    bool later_i = (a < b) || (a == b && ia > ib);
                    bool up = ((i & k) == 0);
                    if (later_i == up) { sk[i] = b; sk[ixj] = a; si[i] = ib; si[ixj] = ia; }
                }
            }
            __syncthreads();
        }
    }
    for (int r = tid; r < KSEL; r += 256) {
        int gid = g * NPG + si[r];
        int p = g * KSEL + r;
        perm[p] = gid;
        newidx[gid] = p;
    }
}

// xp (gated pooled feat) fused into GAT feature transform
__global__ __launch_bounds__(256) void k_gatfeat(const int* __restrict__ perm, const float* __restrict__ x1,
                                                 const float* __restrict__ score, const float* __restrict__ Wg,
                                                 const float* __restrict__ a_src, const float* __restrict__ a_dst,
                                                 float* __restrict__ hfeat, float* __restrict__ als,
                                                 float* __restrict__ ald) {
    int p = blockIdx.x * blockDim.x + threadIdx.x;
    if (p >= NK) return;
    int gid = perm[p];
    float t = tanhf(score[gid]);
    float xi[10];
#pragma unroll
    for (int k = 0; k < 10; k++) xi[k] = x1[(size_t)gid * 10 + k] * t;
    for (int hh = 0; hh < NH; hh++) {
        float as_ = 0.f, ad_ = 0.f;
#pragma unroll
        for (int c = 0; c < NC; c++) {
            int j = hh * NC + c;
            float v = 0.f;
#pragma unroll
            for (int k = 0; k < 10; k++) v += xi[k] * Wg[k * HC + j];
            hfeat[(size_t)p * HC + j] = v;
            as_ += v * a_src[j];
            ad_ += v * a_dst[j];
        }
        als[p * NH + hh] = as_;
        ald[p * NH + hh] = ad_;
    }
}

// Fused GAT aggregation: online softmax over in-edges + self loop, per (pooled node, head).
__global__ __launch_bounds__(256) void k_gatagg(const int* __restrict__ perm, const int* __restrict__ newidx,
                                                const int* __restrict__ rowptr, const int* __restrict__ rowcnt,
                                                const int* __restrict__ csr_src, const float* __restrict__ als,
                                                const float* __restrict__ ald, const float* __restrict__ hfeat,
                                                float* __restrict__ xg) {
    int t = blockIdx.x * blockDim.x + threadIdx.x;
    if (t >= NK * NH) return;
    int p = t / NH, hh = t - p * NH;
    int d = perm[p];
    float aldp = ald[p * NH + hh];
    float m = leaky(als[p * NH + hh] + aldp);   // self-loop logit
    float wsum = 1.f;
    float acc[NC];
    const float* hp = hfeat + (size_t)p * HC + hh * NC;
#pragma unroll
    for (int c = 0; c < NC; c++) acc[c] = hp[c];
    int p0 = rowptr[d], cnt = rowcnt[d];
    for (int e = p0; e < p0 + cnt; e++) {
        int s = csr_src[e];
        int s2 = newidx[s];
        if (s2 < 0) continue;
        float l = leaky(als[s2 * NH + hh] + aldp);
        const float* hsrc = hfeat + (size_t)s2 * HC + hh * NC;
        if (l > m) {
            float sc = expf(m - l);
            wsum = wsum * sc + 1.f;
#pragma unroll
            for (int c = 0; c < NC; c++) acc[c] = acc[c] * sc + hsrc[c];
            m = l;
        } else {
            float w = expf(l - m);
            wsum += w;
#pragma unroll
            for (int c = 0; c < NC; c++) acc[c] += w * hsrc[c];
        }
    }
    float inv = 1.f / wsum;
    float* xo = xg + (size_t)p * HC + hh * NC;
#pragma unroll
    for (int c = 0; c < NC; c++) xo[c] = acc[c] * inv;
}

// per-graph readout: gout[g][j] = sum_r xg + K*bg ; 4 threads per column
__global__ __launch_bounds__(256) void k_readout(const float* __restrict__ xg, const float* __restrict__ bg,
                                                 float* __restrict__ gout) {
    __shared__ float red[256];
    int g = blockIdx.x, t = threadIdx.x;
    float acc = 0.f;
    int j = t >> 2, lane = t & 3;
    if (t < 240) {
        size_t base = (size_t)g * KSEL;
        for (int r = lane; r < KSEL; r += 4)
            acc += xg[(base + r) * HC + j];
    }
    red[t] = acc;
    __syncthreads();
    if (t < 240 && lane == 0)
        gout[g * HC + j] = red[t] + red[t + 1] + red[t + 2] + red[t + 3] + (float)KSEL * bg[j];
}

// final MLP + log_softmax, one thread per graph
__global__ __launch_bounds__(64) void k_mlp(const float* __restrict__ gout, const float* __restrict__ Wf1,
                                            const float* __restrict__ bf1, const float* __restrict__ Wf2,
                                            const float* __restrict__ bf2, float* __restrict__ out) {
    int g = threadIdx.x;
    if (g >= G) return;
    float gi[HC];
#pragma unroll
    for (int k = 0; k < HC; k++) gi[k] = gout[g * HC + k];
    float hid[30];
    for (int j = 0; j < 30; j++) {
        float s = bf1[j];
        for (int k = 0; k < HC; k++) s += gi[k] * Wf1[k * 30 + j];
        hid[j] = s > 0.f ? s : 0.f;
    }
    float z[3];
    for (int j = 0; j < 3; j++) {
        float s = bf2[j];
        for (int k = 0; k < 30; k++) s += hid[k] * Wf2[k * 3 + j];
        z[j] = s;
    }
    float m = fmaxf(z[0], fmaxf(z[1], z[2]));
    float lse = logf(expf(z[0] - m) + expf(z[1] - m) + expf(z[2] - m)) + m;
    for (int j = 0; j < 3; j++) out[g * 3 + j] = z[j] - lse;
}

extern "C" void kernel_launch(void* const* d_in, const int* in_sizes, int n_in,
                              void* d_out, int out_size, void* d_ws, size_t ws_size,
                              hipStream_t stream) {
    const float* x     = (const float*)d_in[0];
    const int*   src   = (const int*)d_in[1];
    const int*   dst   = (const int*)d_in[2];
    const float* W1    = (const float*)d_in[4];
    const float* b1    = (const float*)d_in[5];
    const float* Ws    = (const float*)d_in[6];
    const float* bs    = (const float*)d_in[7];
    const float* Wg    = (const float*)d_in[8];
    const float* a_src = (const float*)d_in[9];
    const float* a_dst = (const float*)d_in[10];
    const float* bg    = (const float*)d_in[11];
    const float* Wf1   = (const float*)d_in[12];
    const float* bf1   = (const float*)d_in[13];
    const float* Wf2   = (const float*)d_in[14];
    const float* bf2   = (const float*)d_in[15];
    float* out = (float*)d_out;

    const size_t N = NTOT;
    float* ws = (float*)d_ws;
    // float region [0, 23N): h1(10N) hs(N) dinv(N) score(N) x1(10N)
    float* h1    = ws;                  // 10N
    float* hs    = h1 + 10 * N;         // N
    float* dinv  = hs + N;              // N
    float* score = dinv + N;            // N
    float* x1    = score + N;           // 10N
    // xg aliases [0, 13N) = h1+hs+dinv+score (all dead by the time xg is written)
    float* xg    = ws;                  // NK*60 = 1.574M floats <= 13N = 1.704M
    int* rowptr  = (int*)(x1 + 10 * N); // N
    int* rowcnt  = rowptr + N;          // N
    int* newidx  = rowcnt + N;          // N
    int* csr_src = newidx + N;          // NE
    int* perm    = csr_src + NE;        // NK
    float* hfeat = (float*)(perm + NK); // NK*60
    float* als   = hfeat + (size_t)NK * HC;  // NK*3
    float* ald   = als + (size_t)NK * NH;    // NK*3
    float* gout  = ald + (size_t)NK * NH;    // G*60

    hipMemsetAsync(newidx, 0xFF, N * sizeof(int), stream);

    k_h1<<<NTOT / 256, 256, 0, stream>>>(x, W1, h1);
    k_csr<<<G, 256, 0, stream>>>(src, dst, dinv, rowptr, rowcnt, csr_src);
    k_gcn10<<<NTOT / 256, 256, 0, stream>>>(h1, dinv, rowptr, rowcnt, csr_src, b1, Ws, x1, hs);
    k_score<<<NTOT / 256, 256, 0, stream>>>(hs, dinv, rowptr, rowcnt, csr_src, bs, score);
    k_topk<<<G, 256, 0, stream>>>(score, perm, newidx);
    k_gatfeat<<<(NK + 255) / 256, 256, 0, stream>>>(perm, x1, score, Wg, a_src, a_dst, hfeat, als, ald);
    k_gatagg<<<(NK * NH + 255) / 256, 256, 0, stream>>>(perm, newidx, rowptr, rowcnt, csr_src, als, ald, hfeat, xg);
    k_readout<<<G, 256, 0, stream>>>(xg, bg, gout);
    k_mlp<<<1, 64, 0, stream>>>(gout, Wf1, bf1, Wf2, bf2, out);
}

// Round 3
// 279.253 us; speedup vs baseline: 3.9735x; 1.1158x over previous
//
#include <hip/hip_runtime.h>
#include <math.h>

#define G    64
#define NPG  2048
#define NTOT (G * NPG)          // 131072
#define EPG  (NPG * 8)          // 16384 edges per graph (contiguous by construction)
#define NE   (NTOT * 8)         // 1048576
#define KSEL 410
#define NK   (G * KSEL)         // 26240
#define NH   3
#define NC   20
#define HC   60

__device__ inline float leaky(float x) { return x >= 0.f ? x : 0.2f * x; }

// h1 = x @ W1   (NTOT x 5) @ (5 x 10)
__global__ __launch_bounds__(256) void k_h1(const float* __restrict__ x, const float* __restrict__ W1,
                                            float* __restrict__ h1) {
    int i = blockIdx.x * blockDim.x + threadIdx.x;
    if (i >= NTOT) return;
    float xi[5];
#pragma unroll
    for (int k = 0; k < 5; k++) xi[k] = x[i * 5 + k];
#pragma unroll
    for (int j = 0; j < 10; j++) {
        float s = 0.f;
#pragma unroll
        for (int k = 0; k < 5; k++) s += xi[k] * W1[k * 10 + j];
        h1[i * 10 + j] = s;
    }
}

// Per-graph dst-CSR build: LDS histogram -> scan -> scatter. Also emits dinv.
__global__ __launch_bounds__(256) void k_csr(const int* __restrict__ src, const int* __restrict__ dst,
                                             float* __restrict__ dinv, int* __restrict__ rowptr,
                                             int* __restrict__ rowcnt, int* __restrict__ csr_src) {
    __shared__ int hist[NPG];
    __shared__ int rs[NPG];
    __shared__ int tsum[256];
    int g = blockIdx.x, tid = threadIdx.x;
    int nbase = g * NPG, ebase = g * EPG;
    for (int i = tid; i < NPG; i += 256) hist[i] = 0;
    __syncthreads();
    for (int e = tid; e < EPG; e += 256)
        atomicAdd(&hist[dst[ebase + e] - nbase], 1);
    __syncthreads();
    // exclusive scan of hist[0..2047] into rs
    int loc[8];
    int s = 0;
    int b8 = tid * 8;
#pragma unroll
    for (int k = 0; k < 8; k++) { loc[k] = s; s += hist[b8 + k]; }
    tsum[tid] = s;
    __syncthreads();
    for (int off = 1; off < 256; off <<= 1) {
        int v = (tid >= off) ? tsum[tid - off] : 0;
        __syncthreads();
        tsum[tid] += v;
        __syncthreads();
    }
    int off0 = tsum[tid] - s;
#pragma unroll
    for (int k = 0; k < 8; k++) rs[b8 + k] = off0 + loc[k];
    __syncthreads();
    for (int i = tid; i < NPG; i += 256) {
        int c = hist[i];
        rowcnt[nbase + i] = c;
        rowptr[nbase + i] = ebase + rs[i];
        dinv[nbase + i] = rsqrtf((float)c + 1.0f);
        hist[i] = 0;                       // becomes cursor
    }
    __syncthreads();
    for (int e = tid; e < EPG; e += 256) {
        int ee = ebase + e;
        int sv = src[ee];
        int dl = dst[ee] - nbase;
        int pos = ebase + rs[dl] + atomicAdd(&hist[dl], 1);
        csr_src[pos] = sv;
    }
}

// Gather GCN (10ch) + finalize + scorer projection, no atomics.
__global__ __launch_bounds__(256) void k_gcn10(const float* __restrict__ h1, const float* __restrict__ dinv,
                                               const int* __restrict__ rowptr, const int* __restrict__ rowcnt,
                                               const int* __restrict__ csr_src, const float* __restrict__ b1,
                                               const float* __restrict__ Ws, float* __restrict__ x1,
                                               float* __restrict__ hs) {
    int i = blockIdx.x * blockDim.x + threadIdx.x;
    if (i >= NTOT) return;
    float di = dinv[i];
    float acc[10];
#pragma unroll
    for (int j = 0; j < 10; j++) acc[j] = 0.f;
    int p0 = rowptr[i], cnt = rowcnt[i];
    for (int e = p0; e < p0 + cnt; e++) {
        int s = csr_src[e];
        float c = dinv[s] * di;
        const float* hp = h1 + (size_t)s * 10;
#pragma unroll
        for (int j = 0; j < 10; j++) acc[j] += hp[j] * c;
    }
    float d2 = di * di;
    float dot = 0.f;
#pragma unroll
    for (int j = 0; j < 10; j++) {
        float v = acc[j] + h1[(size_t)i * 10 + j] * d2 + b1[j];
        x1[(size_t)i * 10 + j] = v;
        dot += v * Ws[j];
    }
    hs[i] = dot;
}

// Gather GCN (scorer, 1ch): score[i] = di*sum(dinv[s]*hs[s]) + hs[i]*di^2 + bs
__global__ __launch_bounds__(256) void k_score(const float* __restrict__ hs, const float* __restrict__ dinv,
                                               const int* __restrict__ rowptr, const int* __restrict__ rowcnt,
                                               const int* __restrict__ csr_src, const float* __restrict__ bs,
                                               float* __restrict__ score) {
    int i = blockIdx.x * blockDim.x + threadIdx.x;
    if (i >= NTOT) return;
    float di = dinv[i];
    int p0 = rowptr[i], cnt = rowcnt[i];
    float a = 0.f;
    for (int e = p0; e < p0 + cnt; e++) {
        int s = csr_src[e];
        a += dinv[s] * hs[s];
    }
    score[i] = di * a + hs[i] * di * di + bs[0];
}

// Per-graph top-K via 8-bit radix select (4 levels) on monotone keys.
// Set-equivalent to jax.lax.top_k (ties -> lowest index), order within perm arbitrary.
__global__ __launch_bounds__(256) void k_topk(const float* __restrict__ score, int* __restrict__ perm,
                                              int* __restrict__ newidx) {
    __shared__ unsigned sk[NPG];
    __shared__ int cnt[256];
    __shared__ int tsum[256];
    __shared__ int bsel, bneed, cursor;
    int g = blockIdx.x, tid = threadIdx.x;
    for (int i = tid; i < NPG; i += 256) {
        unsigned u = __float_as_uint(score[g * NPG + i]);
        sk[i] = (u & 0x80000000u) ? ~u : (u | 0x80000000u);   // monotone: bigger float -> bigger uint
    }
    int need = KSEL;
    unsigned prefixHigh = 0;   // chosen high bits, right-aligned
    __syncthreads();
    for (int level = 24; level >= 0; level -= 8) {
        cnt[tid] = 0;
        __syncthreads();
        for (int i = tid; i < NPG; i += 256) {
            unsigned k = sk[i];
            bool match = (level == 24) || ((k >> (level + 8)) == prefixHigh);
            if (match) atomicAdd(&cnt[(k >> level) & 0xFFu], 1);
        }
        __syncthreads();
        if (tid == 0) {
            int cum = 0, b = 255;
            for (; b > 0; b--) {
                if (cum + cnt[b] >= need) break;
                cum += cnt[b];
            }
            bsel = b;
            bneed = need - cum;   // how many still needed from bucket b downward-refine
        }
        __syncthreads();
        prefixHigh = (prefixHigh << 8) | (unsigned)bsel;
        need = bneed;
        __syncthreads();
    }
    unsigned T = prefixHigh;    // exact K-th largest key; need = #ties to take
    if (tid == 0) cursor = 0;
    __syncthreads();
    // strictly greater than T: any order
    for (int i = tid; i < NPG; i += 256) {
        if (sk[i] > T) {
            int p = g * KSEL + atomicAdd(&cursor, 1);
            int gid = g * NPG + i;
            perm[p] = gid;
            newidx[gid] = p;
        }
    }
    // ties == T: lowest indices first (blocked layout + block scan for stable ranks)
    int b8 = tid * 8;
    int lc = 0;
    int local[8];
#pragma unroll
    for (int k = 0; k < 8; k++)
        if (sk[b8 + k] == T) local[lc++] = b8 + k;
    tsum[tid] = lc;
    __syncthreads();
    int run = lc;
    for (int off = 1; off < 256; off <<= 1) {
        int v = (tid >= off) ? tsum[tid - off] : 0;
        __syncthreads();
        tsum[tid] += v;
        __syncthreads();
    }
    int rank0 = tsum[tid] - run;
    int greaterCnt = KSEL - need;
    for (int j = 0; j < lc; j++) {
        int rank = rank0 + j;
        if (rank < need) {
            int p = g * KSEL + greaterCnt + rank;
            int gid = g * NPG + local[j];
            perm[p] = gid;
            newidx[gid] = p;
        }
    }
}

// xp (gated pooled feat) fused into GAT feature transform
__global__ __launch_bounds__(256) void k_gatfeat(const int* __restrict__ perm, const float* __restrict__ x1,
                                                 const float* __restrict__ score, const float* __restrict__ Wg,
                                                 const float* __restrict__ a_src, const float* __restrict__ a_dst,
                                                 float* __restrict__ hfeat, float* __restrict__ als,
                                                 float* __restrict__ ald) {
    int p = blockIdx.x * blockDim.x + threadIdx.x;
    if (p >= NK) return;
    int gid = perm[p];
    float t = tanhf(score[gid]);
    float xi[10];
#pragma unroll
    for (int k = 0; k < 10; k++) xi[k] = x1[(size_t)gid * 10 + k] * t;
    for (int hh = 0; hh < NH; hh++) {
        float as_ = 0.f, ad_ = 0.f;
#pragma unroll
        for (int c = 0; c < NC; c++) {
            int j = hh * NC + c;
            float v = 0.f;
#pragma unroll
            for (int k = 0; k < 10; k++) v += xi[k] * Wg[k * HC + j];
            hfeat[(size_t)p * HC + j] = v;
            as_ += v * a_src[j];
            ad_ += v * a_dst[j];
        }
        als[p * NH + hh] = as_;
        ald[p * NH + hh] = ad_;
    }
}

// Fused GAT aggregation: online softmax over in-edges + self loop, per (pooled node, head).
__global__ __launch_bounds__(256) void k_gatagg(const int* __restrict__ perm, const int* __restrict__ newidx,
                                                const int* __restrict__ rowptr, const int* __restrict__ rowcnt,
                                                const int* __restrict__ csr_src, const float* __restrict__ als,
                                                const float* __restrict__ ald, const float* __restrict__ hfeat,
                                                float* __restrict__ xg) {
    int t = blockIdx.x * blockDim.x + threadIdx.x;
    if (t >= NK * NH) return;
    int p = t / NH, hh = t - p * NH;
    int d = perm[p];
    float aldp = ald[p * NH + hh];
    float m = leaky(als[p * NH + hh] + aldp);   // self-loop logit
    float wsum = 1.f;
    float acc[NC];
    const float* hp = hfeat + (size_t)p * HC + hh * NC;
#pragma unroll
    for (int c = 0; c < NC; c++) acc[c] = hp[c];
    int p0 = rowptr[d], cnt = rowcnt[d];
    for (int e = p0; e < p0 + cnt; e++) {
        int s = csr_src[e];
        int s2 = newidx[s];
        if (s2 < 0) continue;
        float l = leaky(als[s2 * NH + hh] + aldp);
        const float* hsrc = hfeat + (size_t)s2 * HC + hh * NC;
        if (l > m) {
            float sc = expf(m - l);
            wsum = wsum * sc + 1.f;
#pragma unroll
            for (int c = 0; c < NC; c++) acc[c] = acc[c] * sc + hsrc[c];
            m = l;
        } else {
            float w = expf(l - m);
            wsum += w;
#pragma unroll
            for (int c = 0; c < NC; c++) acc[c] += w * hsrc[c];
        }
    }
    float inv = 1.f / wsum;
    float* xo = xg + (size_t)p * HC + hh * NC;
#pragma unroll
    for (int c = 0; c < NC; c++) xo[c] = acc[c] * inv;
}

// per-graph readout: gout[g][j] = sum_r xg + K*bg ; 4 threads per column
__global__ __launch_bounds__(256) void k_readout(const float* __restrict__ xg, const float* __restrict__ bg,
                                                 float* __restrict__ gout) {
    __shared__ float red[256];
    int g = blockIdx.x, t = threadIdx.x;
    float acc = 0.f;
    int j = t >> 2, lane = t & 3;
    if (t < 240) {
        size_t base = (size_t)g * KSEL;
        for (int r = lane; r < KSEL; r += 4)
            acc += xg[(base + r) * HC + j];
    }
    red[t] = acc;
    __syncthreads();
    if (t < 240 && lane == 0)
        gout[g * HC + j] = red[t] + red[t + 1] + red[t + 2] + red[t + 3] + (float)KSEL * bg[j];
}

// final MLP + log_softmax, one thread per graph
__global__ __launch_bounds__(64) void k_mlp(const float* __restrict__ gout, const float* __restrict__ Wf1,
                                            const float* __restrict__ bf1, const float* __restrict__ Wf2,
                                            const float* __restrict__ bf2, float* __restrict__ out) {
    int g = threadIdx.x;
    if (g >= G) return;
    float gi[HC];
#pragma unroll
    for (int k = 0; k < HC; k++) gi[k] = gout[g * HC + k];
    float hid[30];
    for (int j = 0; j < 30; j++) {
        float s = bf1[j];
        for (int k = 0; k < HC; k++) s += gi[k] * Wf1[k * 30 + j];
        hid[j] = s > 0.f ? s : 0.f;
    }
    float z[3];
    for (int j = 0; j < 3; j++) {
        float s = bf2[j];
        for (int k = 0; k < 30; k++) s += hid[k] * Wf2[k * 3 + j];
        z[j] = s;
    }
    float m = fmaxf(z[0], fmaxf(z[1], z[2]));
    float lse = logf(expf(z[0] - m) + expf(z[1] - m) + expf(z[2] - m)) + m;
    for (int j = 0; j < 3; j++) out[g * 3 + j] = z[j] - lse;
}

extern "C" void kernel_launch(void* const* d_in, const int* in_sizes, int n_in,
                              void* d_out, int out_size, void* d_ws, size_t ws_size,
                              hipStream_t stream) {
    const float* x     = (const float*)d_in[0];
    const int*   src   = (const int*)d_in[1];
    const int*   dst   = (const int*)d_in[2];
    const float* W1    = (const float*)d_in[4];
    const float* b1    = (const float*)d_in[5];
    const float* Ws    = (const float*)d_in[6];
    const float* bs    = (const float*)d_in[7];
    const float* Wg    = (const float*)d_in[8];
    const float* a_src = (const float*)d_in[9];
    const float* a_dst = (const float*)d_in[10];
    const float* bg    = (const float*)d_in[11];
    const float* Wf1   = (const float*)d_in[12];
    const float* bf1   = (const float*)d_in[13];
    const float* Wf2   = (const float*)d_in[14];
    const float* bf2   = (const float*)d_in[15];
    float* out = (float*)d_out;

    const size_t N = NTOT;
    float* ws = (float*)d_ws;
    float* h1    = ws;                  // 10N
    float* hs    = h1 + 10 * N;         // N
    float* dinv  = hs + N;              // N
    float* score = dinv + N;            // N
    float* x1    = score + N;           // 10N
    float* xg    = ws;                  // NK*60 aliases dead h1/hs/dinv/score region
    int* rowptr  = (int*)(x1 + 10 * N); // N
    int* rowcnt  = rowptr + N;          // N
    int* newidx  = rowcnt + N;          // N
    int* csr_src = newidx + N;          // NE
    int* perm    = csr_src + NE;        // NK
    float* hfeat = (float*)(perm + NK); // NK*60
    float* als   = hfeat + (size_t)NK * HC;  // NK*3
    float* ald   = als + (size_t)NK * NH;    // NK*3
    float* gout  = ald + (size_t)NK * NH;    // G*60

    hipMemsetAsync(newidx, 0xFF, N * sizeof(int), stream);

    k_h1<<<NTOT / 256, 256, 0, stream>>>(x, W1, h1);
    k_csr<<<G, 256, 0, stream>>>(src, dst, dinv, rowptr, rowcnt, csr_src);
    k_gcn10<<<NTOT / 256, 256, 0, stream>>>(h1, dinv, rowptr, rowcnt, csr_src, b1, Ws, x1, hs);
    k_score<<<NTOT / 256, 256, 0, stream>>>(hs, dinv, rowptr, rowcnt, csr_src, bs, score);
    k_topk<<<G, 256, 0, stream>>>(score, perm, newidx);
    k_gatfeat<<<(NK + 255) / 256, 256, 0, stream>>>(perm, x1, score, Wg, a_src, a_dst, hfeat, als, ald);
    k_gatagg<<<(NK * NH + 255) / 256, 256, 0, stream>>>(perm, newidx, rowptr, rowcnt, csr_src, als, ald, hfeat, xg);
    k_readout<<<G, 256, 0, stream>>>(xg, bg, gout);
    k_mlp<<<1, 64, 0, stream>>>(gout, Wf1, bf1, Wf2, bf2, out);
}

// Round 4
// 224.254 us; speedup vs baseline: 4.9480x; 1.2453x over previous
//
#include <hip/hip_runtime.h>
#include <math.h>

#define G    64
#define NPG  2048
#define NTOT (G * NPG)          // 131072
#define EPG  (NPG * 8)          // 16384 edges per graph (contiguous by construction)
#define NE   (NTOT * 8)         // 1048576
#define KSEL 410
#define NK   (G * KSEL)         // 26240
#define NH   3
#define NC   20
#define HC   60

__device__ inline float leaky(float x) { return x >= 0.f ? x : 0.2f * x; }

// ---------------------------------------------------------------------------
// Kernel A: one block per graph. h1 -> CSR(LDS) -> GCN10 -> score -> top-K.
// LDS: 81920(h1f) + 32768(csr) + 8192*4(hist,rs,dinvs,hsf) + 4096(tsum) = 151568 B
// ---------------------------------------------------------------------------
__global__ __launch_bounds__(1024) void k_graph(
    const float* __restrict__ x, const int* __restrict__ src, const int* __restrict__ dst,
    const float* __restrict__ W1, const float* __restrict__ b1,
    const float* __restrict__ Ws, const float* __restrict__ bs,
    float* __restrict__ x1g, float* __restrict__ scoreg,
    int* __restrict__ rowptrg, int* __restrict__ rowcntg,
    unsigned short* __restrict__ csrg, int* __restrict__ permg, int* __restrict__ newidxg)
{
    __shared__ float h1f[NPG * 10];          // 80KB; reused later for score/sk/newL
    __shared__ unsigned short csr[EPG];      // 32KB (local src ids)
    __shared__ int hist[NPG];                // histogram -> cursor -> count
    __shared__ int rs[NPG];                  // row starts
    __shared__ float dinvs[NPG];
    __shared__ float hsf[NPG];
    __shared__ int tsum[1024];
    __shared__ int bselS, bneedS, curS;

    int g = blockIdx.x, tid = threadIdx.x;
    int nbase = g * NPG, ebase = g * EPG;

    // P0/P1: zero hist; compute h1 into LDS
    for (int i = tid; i < NPG; i += 1024) hist[i] = 0;
    for (int i = tid; i < NPG; i += 1024) {
        float xi[5];
#pragma unroll
        for (int k = 0; k < 5; k++) xi[k] = x[(size_t)(nbase + i) * 5 + k];
#pragma unroll
        for (int j = 0; j < 10; j++) {
            float s = 0.f;
#pragma unroll
            for (int k = 0; k < 5; k++) s += xi[k] * W1[k * 10 + j];
            h1f[i * 10 + j] = s;
        }
    }
    __syncthreads();
    // P2: histogram of dst
    for (int e = tid; e < EPG; e += 1024)
        atomicAdd(&hist[dst[ebase + e] - nbase], 1);
    __syncthreads();
    // scan (2 bins/thread, Hillis-Steele over 1024 partials)
    int b2 = tid * 2;
    int c0 = hist[b2], c1 = hist[b2 + 1];
    int mysum = c0 + c1;
    tsum[tid] = mysum;
    __syncthreads();
    for (int off = 1; off < 1024; off <<= 1) {
        int v = (tid >= off) ? tsum[tid - off] : 0;
        __syncthreads();
        tsum[tid] += v;
        __syncthreads();
    }
    int off0 = tsum[tid] - mysum;
    rs[b2] = off0;
    rs[b2 + 1] = off0 + c0;
    __syncthreads();
    // rowptr/rowcnt/dinv; reset hist to cursor
    for (int i = tid; i < NPG; i += 1024) {
        int c = hist[i];
        rowcntg[nbase + i] = c;
        rowptrg[nbase + i] = ebase + rs[i];
        dinvs[i] = rsqrtf((float)c + 1.0f);
        hist[i] = 0;
    }
    __syncthreads();
    // P3: scatter into LDS csr (local src ids)
    for (int e = tid; e < EPG; e += 1024) {
        int ee = ebase + e;
        int sl = src[ee] - nbase;
        int dl = dst[ee] - nbase;
        int pos = rs[dl] + atomicAdd(&hist[dl], 1);
        csr[pos] = (unsigned short)sl;
    }
    __syncthreads();
    // P4: coalesced csr writeout (as uints)
    {
        const unsigned* s4 = (const unsigned*)csr;
        unsigned* d4 = (unsigned*)(csrg + ebase);
        for (int w = tid; w < EPG / 2; w += 1024) d4[w] = s4[w];
    }
    // P5: GCN10 gather from LDS
    for (int i = tid; i < NPG; i += 1024) {
        float di = dinvs[i];
        float acc[10];
#pragma unroll
        for (int j = 0; j < 10; j++) acc[j] = 0.f;
        int p0 = rs[i], cnt = hist[i];
        for (int e = p0; e < p0 + cnt; e++) {
            int s = csr[e];
            float c = dinvs[s] * di;
#pragma unroll
            for (int j = 0; j < 10; j++) acc[j] += h1f[s * 10 + j] * c;
        }
        float d2 = di * di;
        float dot = 0.f;
#pragma unroll
        for (int j = 0; j < 10; j++) {
            float v = acc[j] + h1f[i * 10 + j] * d2 + b1[j];
            x1g[(size_t)(nbase + i) * 10 + j] = v;
            dot += v * Ws[j];
        }
        hsf[i] = dot;
    }
    __syncthreads();
    // P6: scorer gather from LDS; score into h1f[0..NPG) (h1 dead)
    float* scoreL = h1f;
    for (int i = tid; i < NPG; i += 1024) {
        float di = dinvs[i];
        int p0 = rs[i], cnt = hist[i];
        float a = 0.f;
        for (int e = p0; e < p0 + cnt; e++) a += dinvs[csr[e]] * hsf[csr[e]];
        float sc = di * a + hsf[i] * di * di + bs[0];
        scoreL[i] = sc;
        scoreg[nbase + i] = sc;
    }
    __syncthreads();
    // P7: radix select top-KSEL on monotone keys (ties -> lowest index)
    unsigned* sk = (unsigned*)(h1f + NPG);       // [NPG]
    int* cntB = (int*)(h1f + 2 * NPG);           // [256]
    int* newL = (int*)(h1f + 2 * NPG + 512);     // [NPG]
    for (int i = tid; i < NPG; i += 1024) {
        unsigned u = __float_as_uint(scoreL[i]);
        sk[i] = (u & 0x80000000u) ? ~u : (u | 0x80000000u);
        newL[i] = -1;
    }
    int need = KSEL;
    unsigned prefix = 0;
    __syncthreads();
    for (int level = 24; level >= 0; level -= 8) {
        if (tid < 256) cntB[tid] = 0;
        __syncthreads();
        for (int i = tid; i < NPG; i += 1024) {
            unsigned k = sk[i];
            bool match = (level == 24) || ((k >> (level + 8)) == prefix);
            if (match) atomicAdd(&cntB[(k >> level) & 0xFFu], 1);
        }
        __syncthreads();
        if (tid == 0) {
            int cum = 0, b = 255;
            for (; b > 0; b--) {
                if (cum + cntB[b] >= need) break;
                cum += cntB[b];
            }
            bselS = b;
            bneedS = need - cum;
        }
        __syncthreads();
        prefix = (prefix << 8) | (unsigned)bselS;
        need = bneedS;
        __syncthreads();
    }
    unsigned T = prefix;
    if (tid == 0) curS = 0;
    __syncthreads();
    for (int i = tid; i < NPG; i += 1024) {
        if (sk[i] > T) {
            int p = g * KSEL + atomicAdd(&curS, 1);
            permg[p] = nbase + i;
            newL[i] = p;
        }
    }
    // ties (== T): lowest indices first via blocked scan
    int lc = 0;
    int loc2[2];
#pragma unroll
    for (int k = 0; k < 2; k++)
        if (sk[b2 + k] == T) loc2[lc++] = b2 + k;
    __syncthreads();
    tsum[tid] = lc;
    __syncthreads();
    for (int off = 1; off < 1024; off <<= 1) {
        int v = (tid >= off) ? tsum[tid - off] : 0;
        __syncthreads();
        tsum[tid] += v;
        __syncthreads();
    }
    int rank0 = tsum[tid] - lc;
    int greaterCnt = KSEL - need;
    for (int j = 0; j < lc; j++) {
        int rank = rank0 + j;
        if (rank < need) {
            int p = g * KSEL + greaterCnt + rank;
            permg[p] = nbase + loc2[j];
            newL[loc2[j]] = p;
        }
    }
    __syncthreads();
    for (int i = tid; i < NPG; i += 1024) newidxg[nbase + i] = newL[i];
}

// ---------------------------------------------------------------------------
// Kernel B: one block per graph. GAT feat + online-softmax agg + readout.
// LDS total ~137992 B
// ---------------------------------------------------------------------------
__global__ __launch_bounds__(1024) void k_gat(
    const float* __restrict__ x1g, const float* __restrict__ scoreg,
    const int* __restrict__ permg, const int* __restrict__ newidxg,
    const int* __restrict__ rowptrg, const int* __restrict__ rowcntg,
    const unsigned short* __restrict__ csrg,
    const float* __restrict__ Wg, const float* __restrict__ a_srcw,
    const float* __restrict__ a_dstw, const float* __restrict__ bg,
    float* __restrict__ goutg)
{
    __shared__ float hfeat[KSEL * HC];   // 98400 B
    __shared__ float alsL[KSEL * NH];
    __shared__ float aldL[KSEL * NH];
    __shared__ int newL[NPG];            // local pooled idx or -1
    __shared__ int rpL[KSEL];
    __shared__ int rcL[KSEL];
    __shared__ float xi[KSEL * 10];      // gated pooled features
    __shared__ float goutL[HC];

    int g = blockIdx.x, tid = threadIdx.x;
    int nbase = g * NPG;

    for (int i = tid; i < NPG; i += 1024) {
        int v = newidxg[nbase + i];
        newL[i] = (v >= 0) ? (v - g * KSEL) : -1;
    }
    for (int p = tid; p < KSEL; p += 1024) {
        int gid = permg[g * KSEL + p];
        rpL[p] = rowptrg[gid];
        rcL[p] = rowcntg[gid];
        float t = tanhf(scoreg[gid]);
#pragma unroll
        for (int k = 0; k < 10; k++) xi[p * 10 + k] = x1g[(size_t)gid * 10 + k] * t;
    }
    if (tid < HC) goutL[tid] = 0.f;
    __syncthreads();
    // hfeat = xi @ Wg  (tasks: 410*60)
    for (int idx = tid; idx < KSEL * HC; idx += 1024) {
        int p = idx / HC, j = idx - p * HC;
        float v = 0.f;
#pragma unroll
        for (int k = 0; k < 10; k++) v += xi[p * 10 + k] * Wg[k * HC + j];
        hfeat[p * HC + j] = v;
    }
    __syncthreads();
    // attention dots
    for (int t = tid; t < KSEL * NH; t += 1024) {
        int p = t / NH, hh = t - p * NH;
        float as_ = 0.f, ad_ = 0.f;
#pragma unroll
        for (int c = 0; c < NC; c++) {
            float v = hfeat[p * HC + hh * NC + c];
            as_ += v * a_srcw[hh * NC + c];
            ad_ += v * a_dstw[hh * NC + c];
        }
        alsL[p * NH + hh] = as_;
        aldL[p * NH + hh] = ad_;
    }
    __syncthreads();
    // online-softmax aggregation per (pooled node, head) + fused readout
    for (int t = tid; t < KSEL * NH; t += 1024) {
        int p = t / NH, hh = t - p * NH;
        float aldp = aldL[p * NH + hh];
        float m = leaky(alsL[p * NH + hh] + aldp);   // self loop
        float wsum = 1.f;
        float acc[NC];
        const float* hp = hfeat + p * HC + hh * NC;
#pragma unroll
        for (int c = 0; c < NC; c++) acc[c] = hp[c];
        int rp = rpL[p], rc = rcL[p];
        for (int e = 0; e < rc; e++) {
            int s = csrg[rp + e];
            int s2 = newL[s];
            if (s2 < 0) continue;
            float l = leaky(alsL[s2 * NH + hh] + aldp);
            const float* hsrc = hfeat + s2 * HC + hh * NC;
            if (l > m) {
                float sc = expf(m - l);
                wsum = wsum * sc + 1.f;
#pragma unroll
                for (int c = 0; c < NC; c++) acc[c] = acc[c] * sc + hsrc[c];
                m = l;
            } else {
                float w = expf(l - m);
                wsum += w;
#pragma unroll
                for (int c = 0; c < NC; c++) acc[c] += w * hsrc[c];
            }
        }
        float inv = 1.f / wsum;
#pragma unroll
        for (int c = 0; c < NC; c++) atomicAdd(&goutL[hh * NC + c], acc[c] * inv);
    }
    __syncthreads();
    if (tid < HC) goutg[g * HC + tid] = goutL[tid] + (float)KSEL * bg[tid];
}

// final MLP + log_softmax, one thread per graph
__global__ __launch_bounds__(64) void k_mlp(const float* __restrict__ gout, const float* __restrict__ Wf1,
                                            const float* __restrict__ bf1, const float* __restrict__ Wf2,
                                            const float* __restrict__ bf2, float* __restrict__ out) {
    int g = threadIdx.x;
    if (g >= G) return;
    float gi[HC];
#pragma unroll
    for (int k = 0; k < HC; k++) gi[k] = gout[g * HC + k];
    float hid[30];
    for (int j = 0; j < 30; j++) {
        float s = bf1[j];
        for (int k = 0; k < HC; k++) s += gi[k] * Wf1[k * 30 + j];
        hid[j] = s > 0.f ? s : 0.f;
    }
    float z[3];
    for (int j = 0; j < 3; j++) {
        float s = bf2[j];
        for (int k = 0; k < 30; k++) s += hid[k] * Wf2[k * 3 + j];
        z[j] = s;
    }
    float m = fmaxf(z[0], fmaxf(z[1], z[2]));
    float lse = logf(expf(z[0] - m) + expf(z[1] - m) + expf(z[2] - m)) + m;
    for (int j = 0; j < 3; j++) out[g * 3 + j] = z[j] - lse;
}

extern "C" void kernel_launch(void* const* d_in, const int* in_sizes, int n_in,
                              void* d_out, int out_size, void* d_ws, size_t ws_size,
                              hipStream_t stream) {
    const float* x     = (const float*)d_in[0];
    const int*   src   = (const int*)d_in[1];
    const int*   dst   = (const int*)d_in[2];
    const float* W1    = (const float*)d_in[4];
    const float* b1    = (const float*)d_in[5];
    const float* Ws    = (const float*)d_in[6];
    const float* bs    = (const float*)d_in[7];
    const float* Wg    = (const float*)d_in[8];
    const float* a_src = (const float*)d_in[9];
    const float* a_dst = (const float*)d_in[10];
    const float* bg    = (const float*)d_in[11];
    const float* Wf1   = (const float*)d_in[12];
    const float* bf1   = (const float*)d_in[13];
    const float* Wf2   = (const float*)d_in[14];
    const float* bf2   = (const float*)d_in[15];
    float* out = (float*)d_out;

    const size_t N = NTOT;
    float* ws = (float*)d_ws;
    float* x1g    = ws;                         // 10N
    float* scoreg = x1g + 10 * N;               // N
    int* rowptrg  = (int*)(scoreg + N);         // N
    int* rowcntg  = rowptrg + N;                // N
    int* newidxg  = rowcntg + N;                // N
    int* permg    = newidxg + N;                // NK
    float* goutg  = (float*)(permg + NK);       // G*60
    unsigned short* csrg = (unsigned short*)(goutg + G * HC);  // NE ushort

    k_graph<<<G, 1024, 0, stream>>>(x, src, dst, W1, b1, Ws, bs,
                                    x1g, scoreg, rowptrg, rowcntg, csrg, permg, newidxg);
    k_gat<<<G, 1024, 0, stream>>>(x1g, scoreg, permg, newidxg, rowptrg, rowcntg, csrg,
                                  Wg, a_src, a_dst, bg, goutg);
    k_mlp<<<1, 64, 0, stream>>>(goutg, Wf1, bf1, Wf2, bf2, out);
}

// Round 5
// 201.630 us; speedup vs baseline: 5.5032x; 1.1122x over previous
//
#include <hip/hip_runtime.h>
#include <math.h>

#define G    64
#define NPG  2048
#define NTOT (G * NPG)          // 131072
#define EPG  (NPG * 8)          // 16384 edges per graph (contiguous by construction)
#define NE   (NTOT * 8)         // 1048576
#define KSEL 410
#define NK   (G * KSEL)         // 26240
#define NH   3
#define NC   20
#define HC   60
#define KPAD 512                // padded pooled-node count for reductions

__device__ inline float leaky(float x) { return x >= 0.f ? x : 0.2f * x; }

// ---------------------------------------------------------------------------
// 1. h1 = x @ W1  (full grid)
// ---------------------------------------------------------------------------
__global__ __launch_bounds__(256) void k_h1(const float* __restrict__ x, const float* __restrict__ W1,
                                            float* __restrict__ h1) {
    int i = blockIdx.x * blockDim.x + threadIdx.x;
    if (i >= NTOT) return;
    float xi[5];
#pragma unroll
    for (int k = 0; k < 5; k++) xi[k] = x[i * 5 + k];
#pragma unroll
    for (int j = 0; j < 10; j++) {
        float s = 0.f;
#pragma unroll
        for (int k = 0; k < 5; k++) s += xi[k] * W1[k * 10 + j];
        h1[i * 10 + j] = s;
    }
}

// ---------------------------------------------------------------------------
// 2. Per-graph dst-CSR build fully in LDS; coalesced writeout. ~52 KB LDS.
//    rowcnt eliminated: rowptr has a sentinel (rowptr[NTOT]=NE; per-graph scan
//    boundaries make rowptr[i+1]-rowptr[i] valid everywhere).
// ---------------------------------------------------------------------------
__global__ __launch_bounds__(1024) void k_csr(const int* __restrict__ src, const int* __restrict__ dst,
                                              float* __restrict__ dinvg, int* __restrict__ rowptrg,
                                              unsigned short* __restrict__ csrg) {
    __shared__ int hist[NPG];
    __shared__ int rs[NPG];
    __shared__ unsigned short csr[EPG];
    __shared__ int tsum[1024];
    int g = blockIdx.x, tid = threadIdx.x;
    int nbase = g * NPG, ebase = g * EPG;

    for (int i = tid; i < NPG; i += 1024) hist[i] = 0;
    __syncthreads();
    for (int e = tid; e < EPG; e += 1024)
        atomicAdd(&hist[dst[ebase + e] - nbase], 1);
    __syncthreads();
    // exclusive scan (2 bins/thread)
    int b2 = tid * 2;
    int c0 = hist[b2], c1 = hist[b2 + 1];
    int mysum = c0 + c1;
    tsum[tid] = mysum;
    __syncthreads();
    for (int off = 1; off < 1024; off <<= 1) {
        int v = (tid >= off) ? tsum[tid - off] : 0;
        __syncthreads();
        tsum[tid] += v;
        __syncthreads();
    }
    int off0 = tsum[tid] - mysum;
    rs[b2] = off0;
    rs[b2 + 1] = off0 + c0;
    __syncthreads();
    for (int i = tid; i < NPG; i += 1024) {
        int c = hist[i];
        rowptrg[nbase + i] = ebase + rs[i];
        dinvg[nbase + i] = rsqrtf((float)c + 1.0f);
        hist[i] = 0;                       // becomes cursor
    }
    if (g == G - 1 && tid == 0) rowptrg[NTOT] = NE;   // sentinel
    __syncthreads();
    for (int e = tid; e < EPG; e += 1024) {
        int ee = ebase + e;
        int sl = src[ee] - nbase;
        int dl = dst[ee] - nbase;
        int pos = rs[dl] + atomicAdd(&hist[dl], 1);
        csr[pos] = (unsigned short)sl;
    }
    __syncthreads();
    {   // coalesced writeout as uints
        const unsigned* s4 = (const unsigned*)csr;
        unsigned* d4 = (unsigned*)(csrg + ebase);
        for (int w = tid; w < EPG / 2; w += 1024) d4[w] = s4[w];
    }
}

// ---------------------------------------------------------------------------
// 3. GCN10 gather (full grid, 1 node/thread) + scorer projection hs.
//    csr reads are coalesced (rowptr ranges tile contiguously across lanes).
// ---------------------------------------------------------------------------
__global__ __launch_bounds__(256) void k_gcn10(const float* __restrict__ h1, const float* __restrict__ dinvg,
                                               const int* __restrict__ rowptrg, const unsigned short* __restrict__ csrg,
                                               const float* __restrict__ b1, const float* __restrict__ Ws,
                                               float* __restrict__ x1g, float* __restrict__ hsg) {
    int i = blockIdx.x * blockDim.x + threadIdx.x;
    if (i >= NTOT) return;
    int nbase = (i >> 11) << 11;
    float di = dinvg[i];
    float acc[10];
#pragma unroll
    for (int j = 0; j < 10; j++) acc[j] = 0.f;
    int p0 = rowptrg[i], p1 = rowptrg[i + 1];
    for (int e = p0; e < p1; e++) {
        int s = nbase + csrg[e];
        float c = dinvg[s] * di;
        const float* hp = h1 + (size_t)s * 10;
#pragma unroll
        for (int j = 0; j < 10; j++) acc[j] += hp[j] * c;
    }
    float d2 = di * di;
    float dot = 0.f;
#pragma unroll
    for (int j = 0; j < 10; j++) {
        float v = acc[j] + h1[(size_t)i * 10 + j] * d2 + b1[j];
        x1g[(size_t)i * 10 + j] = v;
        dot += v * Ws[j];
    }
    hsg[i] = dot;
}

// ---------------------------------------------------------------------------
// 4. Per-graph: scorer gather (hs/dinv staged in LDS) + radix-select top-K.
//    ~45 KB LDS. Ties -> lowest index (matches jax.lax.top_k as a set).
// ---------------------------------------------------------------------------
__global__ __launch_bounds__(1024) void k_scoretopk(const float* __restrict__ hsg, const float* __restrict__ dinvg,
                                                    const int* __restrict__ rowptrg, const unsigned short* __restrict__ csrg,
                                                    const float* __restrict__ bs, float* __restrict__ scoreg,
                                                    int* __restrict__ permg, int* __restrict__ newidxg) {
    __shared__ float dinvs[NPG];
    __shared__ float hsf[NPG];
    __shared__ float scoreL[NPG];
    __shared__ unsigned sk[NPG];
    __shared__ int newL[NPG];
    __shared__ int tsum[1024];
    __shared__ int cntB[256];
    __shared__ int bselS, bneedS, curS;
    int g = blockIdx.x, tid = threadIdx.x;
    int nbase = g * NPG;

    for (int i = tid; i < NPG; i += 1024) {
        dinvs[i] = dinvg[nbase + i];
        hsf[i] = hsg[nbase + i];
        newL[i] = -1;
    }
    __syncthreads();
    float bsv = bs[0];
    for (int i = tid; i < NPG; i += 1024) {
        float di = dinvs[i];
        int p0 = rowptrg[nbase + i], p1 = rowptrg[nbase + i + 1];
        float a = 0.f;
        for (int e = p0; e < p1; e++) {
            int s = csrg[e];
            a += dinvs[s] * hsf[s];
        }
        float sc = di * a + hsf[i] * di * di + bsv;
        scoreL[i] = sc;
        scoreg[nbase + i] = sc;
        unsigned u = __float_as_uint(sc);
        sk[i] = (u & 0x80000000u) ? ~u : (u | 0x80000000u);
    }
    int need = KSEL;
    unsigned prefix = 0;
    __syncthreads();
    for (int level = 24; level >= 0; level -= 8) {
        if (tid < 256) cntB[tid] = 0;
        __syncthreads();
        for (int i = tid; i < NPG; i += 1024) {
            unsigned k = sk[i];
            bool match = (level == 24) || ((k >> (level + 8)) == prefix);
            if (match) atomicAdd(&cntB[(k >> level) & 0xFFu], 1);
        }
        __syncthreads();
        if (tid == 0) {
            int cum = 0, b = 255;
            for (; b > 0; b--) {
                if (cum + cntB[b] >= need) break;
                cum += cntB[b];
            }
            bselS = b;
            bneedS = need - cum;
        }
        __syncthreads();
        prefix = (prefix << 8) | (unsigned)bselS;
        need = bneedS;
        __syncthreads();
    }
    unsigned T = prefix;
    if (tid == 0) curS = 0;
    __syncthreads();
    for (int i = tid; i < NPG; i += 1024) {
        if (sk[i] > T) {
            int p = g * KSEL + atomicAdd(&curS, 1);
            permg[p] = nbase + i;
            newL[i] = p;
        }
    }
    // ties == T: lowest indices first via blocked scan
    int b2 = tid * 2;
    int lc = 0;
    int loc2[2];
#pragma unroll
    for (int k = 0; k < 2; k++)
        if (sk[b2 + k] == T) loc2[lc++] = b2 + k;
    __syncthreads();
    tsum[tid] = lc;
    __syncthreads();
    for (int off = 1; off < 1024; off <<= 1) {
        int v = (tid >= off) ? tsum[tid - off] : 0;
        __syncthreads();
        tsum[tid] += v;
        __syncthreads();
    }
    int rank0 = tsum[tid] - lc;
    int greaterCnt = KSEL - need;
    for (int j = 0; j < lc; j++) {
        int rank = rank0 + j;
        if (rank < need) {
            int p = g * KSEL + greaterCnt + rank;
            permg[p] = nbase + loc2[j];
            newL[loc2[j]] = p;
        }
    }
    __syncthreads();
    for (int i = tid; i < NPG; i += 1024) newidxg[nbase + i] = newL[i];
}

// ---------------------------------------------------------------------------
// 5. GAT per (graph, head): features + branchless online-softmax agg +
//    tree-reduced readout. 192 blocks x 512 thr, ~53 KB LDS, no atomics.
// ---------------------------------------------------------------------------
__global__ __launch_bounds__(512) void k_gat(
    const float* __restrict__ x1g, const float* __restrict__ scoreg,
    const int* __restrict__ permg, const int* __restrict__ newidxg,
    const int* __restrict__ rowptrg, const unsigned short* __restrict__ csrg,
    const float* __restrict__ Wg, const float* __restrict__ a_srcw,
    const float* __restrict__ a_dstw, const float* __restrict__ bg,
    float* __restrict__ goutg)
{
    __shared__ float hfeatH[KPAD * NC];   // 40 KB
    __shared__ float alsH[KPAD];
    __shared__ float aldH[KPAD];
    __shared__ short newLs[NPG];          // 4 KB
    __shared__ int rpL[KPAD];
    __shared__ int rcL[KPAD];
    __shared__ float wgs[10 * NC];
    __shared__ float asr[NC], adr[NC];

    int b = blockIdx.x, tid = threadIdx.x;
    int g = b / NH, hh = b - g * NH;
    int nbase = g * NPG, gK = g * KSEL;

    for (int i = tid; i < NPG; i += 512) {
        int v = newidxg[nbase + i];
        newLs[i] = (short)(v >= 0 ? v - gK : -1);
    }
    for (int t = tid; t < 10 * NC; t += 512) {
        int k = t / NC, c = t - k * NC;
        wgs[t] = Wg[k * HC + hh * NC + c];
    }
    if (tid < NC) { asr[tid] = a_srcw[hh * NC + tid]; adr[tid] = a_dstw[hh * NC + tid]; }
    __syncthreads();
    for (int p = tid; p < KSEL; p += 512) {
        int gid = permg[gK + p];
        int rp = rowptrg[gid];
        rpL[p] = rp;
        rcL[p] = rowptrg[gid + 1] - rp;
        float tt = tanhf(scoreg[gid]);
        float xi[10];
#pragma unroll
        for (int k = 0; k < 10; k++) xi[k] = x1g[(size_t)gid * 10 + k] * tt;
        float as_ = 0.f, ad_ = 0.f;
#pragma unroll
        for (int c = 0; c < NC; c++) {
            float v = 0.f;
#pragma unroll
            for (int k = 0; k < 10; k++) v += xi[k] * wgs[k * NC + c];
            hfeatH[p * NC + c] = v;
            as_ += v * asr[c];
            ad_ += v * adr[c];
        }
        alsH[p] = as_;
        aldH[p] = ad_;
    }
    __syncthreads();
    // branchless online softmax over surviving in-edges + self loop
    float res[NC];
    bool active = (tid < KSEL);
    if (active) {
        int p = tid;
        float aldp = aldH[p];
        float m = leaky(alsH[p] + aldp);
        float wsum = 1.f;
#pragma unroll
        for (int c = 0; c < NC; c++) res[c] = hfeatH[p * NC + c];
        int rp = rpL[p], rc = rcL[p];
        for (int e = 0; e < rc; e++) {
            int s = csrg[rp + e];
            int s2 = newLs[s];
            if (s2 < 0) continue;
            float l = leaky(alsH[s2] + aldp);
            float nm = fmaxf(m, l);
            float sc = expf(m - nm);
            float w = expf(l - nm);
            wsum = wsum * sc + w;
            const float* hsrc = hfeatH + s2 * NC;
#pragma unroll
            for (int c = 0; c < NC; c++) res[c] = res[c] * sc + w * hsrc[c];
            m = nm;
        }
        float inv = 1.f / wsum;
#pragma unroll
        for (int c = 0; c < NC; c++) res[c] *= inv;
    }
    __syncthreads();
    // writeback (pad rows zero) then tree-reduce over p
#pragma unroll
    for (int c = 0; c < NC; c++) hfeatH[tid * NC + c] = active ? res[c] : 0.f;
    __syncthreads();
    for (int off = 256; off >= 1; off >>= 1) {
        for (int idx = tid; idx < off * NC; idx += 512) {
            int r = idx / NC, c = idx - r * NC;
            hfeatH[r * NC + c] += hfeatH[(r + off) * NC + c];
        }
        __syncthreads();
    }
    if (tid < NC)
        goutg[g * HC + hh * NC + tid] = hfeatH[tid] + (float)KSEL * bg[hh * NC + tid];
}

// ---------------------------------------------------------------------------
// 6. final MLP + log_softmax
// ---------------------------------------------------------------------------
__global__ __launch_bounds__(64) void k_mlp(const float* __restrict__ gout, const float* __restrict__ Wf1,
                                            const float* __restrict__ bf1, const float* __restrict__ Wf2,
                                            const float* __restrict__ bf2, float* __restrict__ out) {
    int g = threadIdx.x;
    if (g >= G) return;
    float gi[HC];
#pragma unroll
    for (int k = 0; k < HC; k++) gi[k] = gout[g * HC + k];
    float hid[30];
    for (int j = 0; j < 30; j++) {
        float s = bf1[j];
        for (int k = 0; k < HC; k++) s += gi[k] * Wf1[k * 30 + j];
        hid[j] = s > 0.f ? s : 0.f;
    }
    float z[3];
    for (int j = 0; j < 3; j++) {
        float s = bf2[j];
        for (int k = 0; k < 30; k++) s += hid[k] * Wf2[k * 3 + j];
        z[j] = s;
    }
    float m = fmaxf(z[0], fmaxf(z[1], z[2]));
    float lse = logf(expf(z[0] - m) + expf(z[1] - m) + expf(z[2] - m)) + m;
    for (int j = 0; j < 3; j++) out[g * 3 + j] = z[j] - lse;
}

extern "C" void kernel_launch(void* const* d_in, const int* in_sizes, int n_in,
                              void* d_out, int out_size, void* d_ws, size_t ws_size,
                              hipStream_t stream) {
    const float* x     = (const float*)d_in[0];
    const int*   src   = (const int*)d_in[1];
    const int*   dst   = (const int*)d_in[2];
    const float* W1    = (const float*)d_in[4];
    const float* b1    = (const float*)d_in[5];
    const float* Ws    = (const float*)d_in[6];
    const float* bs    = (const float*)d_in[7];
    const float* Wg    = (const float*)d_in[8];
    const float* a_src = (const float*)d_in[9];
    const float* a_dst = (const float*)d_in[10];
    const float* bg    = (const float*)d_in[11];
    const float* Wf1   = (const float*)d_in[12];
    const float* bf1   = (const float*)d_in[13];
    const float* Wf2   = (const float*)d_in[14];
    const float* bf2   = (const float*)d_in[15];
    float* out = (float*)d_out;

    const size_t N = NTOT;
    float* ws = (float*)d_ws;
    float* h1g    = ws;                          // 10N
    float* x1g    = h1g + 10 * N;                // 10N
    float* hsg    = x1g + 10 * N;                // N
    float* dinvg  = hsg + N;                     // N
    float* scoreg = dinvg + N;                   // N
    int* rowptrg  = (int*)(scoreg + N);          // N+1
    int* newidxg  = rowptrg + N + 1;             // N
    int* permg    = newidxg + N;                 // NK
    float* goutg  = (float*)(permg + NK);        // G*HC
    unsigned short* csrg = (unsigned short*)(goutg + G * HC);  // NE ushort

    k_h1<<<NTOT / 256, 256, 0, stream>>>(x, W1, h1g);
    k_csr<<<G, 1024, 0, stream>>>(src, dst, dinvg, rowptrg, csrg);
    k_gcn10<<<NTOT / 256, 256, 0, stream>>>(h1g, dinvg, rowptrg, csrg, b1, Ws, x1g, hsg);
    k_scoretopk<<<G, 1024, 0, stream>>>(hsg, dinvg, rowptrg, csrg, bs, scoreg, permg, newidxg);
    k_gat<<<G * NH, 512, 0, stream>>>(x1g, scoreg, permg, newidxg, rowptrg, csrg,
                                      Wg, a_src, a_dst, bg, goutg);
    k_mlp<<<1, 64, 0, stream>>>(goutg, Wf1, bf1, Wf2, bf2, out);
}

// Round 6
// 180.269 us; speedup vs baseline: 6.1553x; 1.1185x over previous
//
#include <hip/hip_runtime.h>
#include <math.h>

#define G    64
#define NPG  2048
#define NTOT (G * NPG)          // 131072
#define EPG  (NPG * 8)          // 16384 edges per graph (contiguous by construction)
#define NE   (NTOT * 8)         // 1048576
#define KSEL 410
#define NK   (G * KSEL)         // 26240
#define NH   3
#define NC   20
#define HC   60

__device__ inline float leaky(float x) { return x >= 0.f ? x : 0.2f * x; }

__device__ inline int wave_incl_scan(int v) {
    int lane = threadIdx.x & 63;
#pragma unroll
    for (int d = 1; d < 64; d <<= 1) {
        int t = __shfl_up(v, d, 64);
        if (lane >= d) v += t;
    }
    return v;
}

// ---------------------------------------------------------------------------
// 1. Per-graph CSR build (LDS hist -> wave-shuffle scan -> scatter), fused h1.
//    512 threads, ~48 KB LDS, 5 barriers.
// ---------------------------------------------------------------------------
__global__ __launch_bounds__(512) void k_csr(
    const float* __restrict__ x, const int* __restrict__ src, const int* __restrict__ dst,
    const float* __restrict__ W1, float* __restrict__ h1g, float* __restrict__ dinvg,
    int* __restrict__ rowptrg, unsigned short* __restrict__ csrg)
{
    __shared__ int hist[NPG];
    __shared__ int rs[NPG];
    __shared__ unsigned short csr[EPG];
    __shared__ int wsum[8];
    int g = blockIdx.x, tid = threadIdx.x;
    int nbase = g * NPG, ebase = g * EPG;

    for (int i = tid; i < NPG; i += 512) hist[i] = 0;
    // fused h1 = x @ W1 (independent of CSR phases)
    for (int i = tid; i < NPG; i += 512) {
        float xi[5];
#pragma unroll
        for (int k = 0; k < 5; k++) xi[k] = x[(size_t)(nbase + i) * 5 + k];
#pragma unroll
        for (int j = 0; j < 10; j++) {
            float s = 0.f;
#pragma unroll
            for (int k = 0; k < 5; k++) s += xi[k] * W1[k * 10 + j];
            h1g[(size_t)(nbase + i) * 10 + j] = s;
        }
    }
    __syncthreads();
    for (int e = tid; e < EPG; e += 512)
        atomicAdd(&hist[dst[ebase + e] - nbase], 1);
    __syncthreads();
    // blocked exclusive scan: 4 bins/thread, wave shuffles, 8 wave partials
    int b4 = tid * 4;
    int v[4], loc[4], s = 0;
#pragma unroll
    for (int k = 0; k < 4; k++) { v[k] = hist[b4 + k]; loc[k] = s; s += v[k]; }
    int incl = wave_incl_scan(s);
    int wid = tid >> 6;
    if ((tid & 63) == 63) wsum[wid] = incl;
    __syncthreads();
    if (tid == 0) {
        int a = 0;
#pragma unroll
        for (int w = 0; w < 8; w++) { int t = wsum[w]; wsum[w] = a; a += t; }
    }
    __syncthreads();
    int base = wsum[wid] + incl - s;
#pragma unroll
    for (int k = 0; k < 4; k++) {
        int b = b4 + k, E = base + loc[k];
        rs[b] = E;
        rowptrg[nbase + b] = ebase + E;
        dinvg[nbase + b] = rsqrtf((float)v[k] + 1.0f);
        hist[b] = 0;                        // becomes cursor
    }
    if (g == G - 1 && tid == 0) rowptrg[NTOT] = NE;   // sentinel
    __syncthreads();
    for (int e = tid; e < EPG; e += 512) {
        int ee = ebase + e;
        int sl = src[ee] - nbase;
        int dl = dst[ee] - nbase;
        int pos = rs[dl] + atomicAdd(&hist[dl], 1);
        csr[pos] = (unsigned short)sl;
    }
    __syncthreads();
    {   // coalesced writeout
        const unsigned* s4 = (const unsigned*)csr;
        unsigned* d4 = (unsigned*)(csrg + ebase);
        for (int w = tid; w < EPG / 2; w += 512) d4[w] = s4[w];
    }
}

// ---------------------------------------------------------------------------
// 2. GCN10 gather (full grid) + scorer projection hs. Zero barriers.
// ---------------------------------------------------------------------------
__global__ __launch_bounds__(256) void k_gcn10(const float* __restrict__ h1, const float* __restrict__ dinvg,
                                               const int* __restrict__ rowptrg, const unsigned short* __restrict__ csrg,
                                               const float* __restrict__ b1, const float* __restrict__ Ws,
                                               float* __restrict__ x1g, float* __restrict__ hsg) {
    int i = blockIdx.x * blockDim.x + threadIdx.x;
    if (i >= NTOT) return;
    int nbase = i & ~(NPG - 1);
    float di = dinvg[i];
    float acc[10];
#pragma unroll
    for (int j = 0; j < 10; j++) acc[j] = 0.f;
    int p0 = rowptrg[i], p1 = rowptrg[i + 1];
    for (int e = p0; e < p1; e++) {
        int s = nbase + csrg[e];
        float c = dinvg[s] * di;
        const float* hp = h1 + (size_t)s * 10;
#pragma unroll
        for (int j = 0; j < 10; j++) acc[j] += hp[j] * c;
    }
    float d2 = di * di;
    float dot = 0.f;
#pragma unroll
    for (int j = 0; j < 10; j++) {
        float v = acc[j] + h1[(size_t)i * 10 + j] * d2 + b1[j];
        x1g[(size_t)i * 10 + j] = v;
        dot += v * Ws[j];
    }
    hsg[i] = dot;
}

// ---------------------------------------------------------------------------
// 3. Scorer GCN gather (full grid). Zero barriers.
// ---------------------------------------------------------------------------
__global__ __launch_bounds__(256) void k_score(const float* __restrict__ hsg, const float* __restrict__ dinvg,
                                               const int* __restrict__ rowptrg, const unsigned short* __restrict__ csrg,
                                               const float* __restrict__ bs, float* __restrict__ scoreg) {
    int i = blockIdx.x * blockDim.x + threadIdx.x;
    if (i >= NTOT) return;
    int nbase = i & ~(NPG - 1);
    float di = dinvg[i];
    int p0 = rowptrg[i], p1 = rowptrg[i + 1];
    float a = 0.f;
    for (int e = p0; e < p1; e++) {
        int s = nbase + csrg[e];
        a += dinvg[s] * hsg[s];
    }
    scoreg[i] = di * a + hsg[i] * di * di + bs[0];
}

// ---------------------------------------------------------------------------
// 4. Per-graph top-K: 3-level (11/11/10-bit) radix select, wave-shuffle
//    suffix sums, 256 threads (4 waves), ~16 barriers.
// ---------------------------------------------------------------------------
__global__ __launch_bounds__(256) void k_topk(const float* __restrict__ scoreg, int* __restrict__ permg,
                                              int* __restrict__ newidxg) {
    __shared__ unsigned sk[NPG];
    __shared__ int newL[NPG];
    __shared__ int bins[NPG];
    __shared__ int wsum[4];
    __shared__ int bselS, bneedS, curS, totS;
    int g = blockIdx.x, tid = threadIdx.x;
    int nbase = g * NPG;
    int wid = tid >> 6;

    for (int i = tid; i < NPG; i += 256) {
        unsigned u = __float_as_uint(scoreg[nbase + i]);
        sk[i] = (u & 0x80000000u) ? ~u : (u | 0x80000000u);
        newL[i] = -1;
        bins[i] = 0;
    }
    if (tid == 0) curS = 0;
    int need = KSEL;
    unsigned prefix = 0;
    __syncthreads();

    for (int lv = 0; lv < 3; lv++) {
        // histogram of matching keys
        for (int i = tid; i < NPG; i += 256) {
            unsigned k = sk[i];
            bool match; unsigned bb;
            if (lv == 0)      { match = true;                       bb = k >> 21; }
            else if (lv == 1) { match = ((k >> 21) == prefix);      bb = (k >> 10) & 0x7FFu; }
            else              { match = ((k >> 10) == prefix);      bb = k & 0x3FFu; }
            if (match) atomicAdd(&bins[bb], 1);
        }
        __syncthreads();
        // blocked forward scan (8 bins/thread); read+zero own bins
        int b8 = tid * 8;
        int v[8], loc[8], s = 0;
#pragma unroll
        for (int k = 0; k < 8; k++) { v[k] = bins[b8 + k]; bins[b8 + k] = 0; loc[k] = s; s += v[k]; }
        int incl = wave_incl_scan(s);
        if ((tid & 63) == 63) wsum[wid] = incl;
        __syncthreads();
        if (tid == 0) {
            int a = 0;
#pragma unroll
            for (int w = 0; w < 4; w++) { int t = wsum[w]; wsum[w] = a; a += t; }
            totS = a;
        }
        __syncthreads();
        int base = wsum[wid] + incl - s;
        int tot = totS;
#pragma unroll
        for (int k = 0; k < 8; k++) {
            int Sb = tot - (base + loc[k]);       // count of keys in buckets >= b
            int Sb1 = Sb - v[k];                  // buckets > b
            if (Sb >= need && Sb1 < need) { bselS = b8 + k; bneedS = need - Sb1; }
        }
        __syncthreads();
        if (lv == 0)      prefix = (unsigned)bselS;
        else if (lv == 1) prefix = (prefix << 11) | (unsigned)bselS;
        else              prefix = (prefix << 10) | (unsigned)bselS;
        need = bneedS;
        __syncthreads();
    }
    unsigned T = prefix;            // exact K-th largest key; need = #ties to take

    // strictly greater: any order
    for (int i = tid; i < NPG; i += 256) {
        if (sk[i] > T) {
            int p = g * KSEL + atomicAdd(&curS, 1);
            permg[p] = nbase + i;
            newL[i] = p;
        }
    }
    // ties == T: lowest indices first (blocked ownership + wave scan)
    int b8 = tid * 8;
    int lc = 0, loc[8];
#pragma unroll
    for (int k = 0; k < 8; k++)
        if (sk[b8 + k] == T) loc[lc++] = b8 + k;
    __syncthreads();
    int incl = wave_incl_scan(lc);
    if ((tid & 63) == 63) wsum[wid] = incl;
    __syncthreads();
    if (tid == 0) {
        int a = 0;
#pragma unroll
        for (int w = 0; w < 4; w++) { int t = wsum[w]; wsum[w] = a; a += t; }
    }
    __syncthreads();
    int rank0 = wsum[wid] + incl - lc;
    int greaterCnt = KSEL - need;
    for (int j = 0; j < lc; j++) {
        int rank = rank0 + j;
        if (rank < need) {
            int p = g * KSEL + greaterCnt + rank;
            permg[p] = nbase + loc[j];
            newL[loc[j]] = p;
        }
    }
    __syncthreads();
    for (int i = tid; i < NPG; i += 256) newidxg[nbase + i] = newL[i];
}

// ---------------------------------------------------------------------------
// 5. GAT per (graph, head): features + two-pass softmax agg + butterfly
//    readout. 192 blocks x 512 thr, ~44 KB LDS, ~4 barriers, no atomics.
// ---------------------------------------------------------------------------
__global__ __launch_bounds__(512) void k_gat(
    const float* __restrict__ x1g, const float* __restrict__ scoreg,
    const int* __restrict__ permg, const int* __restrict__ newidxg,
    const int* __restrict__ rowptrg, const unsigned short* __restrict__ csrg,
    const float* __restrict__ Wg, const float* __restrict__ a_srcw,
    const float* __restrict__ a_dstw, const float* __restrict__ bg,
    float* __restrict__ goutg)
{
    __shared__ float hfeatH[KSEL * NC];   // 32.8 KB
    __shared__ float alsH[KSEL];
    __shared__ float aldH[KSEL];
    __shared__ short newLs[NPG];          // 4 KB
    __shared__ int rpL[KSEL];
    __shared__ int rcL[KSEL];
    __shared__ float wgs[10 * NC];
    __shared__ float asr[NC], adr[NC];
    __shared__ float wred[8 * NC];

    int b = blockIdx.x, tid = threadIdx.x;
    int g = b / NH, hh = b - g * NH;
    int nbase = g * NPG, gK = g * KSEL;

    for (int i = tid; i < NPG; i += 512) {
        int v = newidxg[nbase + i];
        newLs[i] = (short)(v >= 0 ? v - gK : -1);
    }
    for (int t = tid; t < 10 * NC; t += 512) {
        int k = t / NC, c = t - k * NC;
        wgs[t] = Wg[k * HC + hh * NC + c];
    }
    if (tid < NC) { asr[tid] = a_srcw[hh * NC + tid]; adr[tid] = a_dstw[hh * NC + tid]; }
    __syncthreads();
    for (int p = tid; p < KSEL; p += 512) {
        int gid = permg[gK + p];
        int rp = rowptrg[gid];
        rpL[p] = rp;
        rcL[p] = rowptrg[gid + 1] - rp;
        float tt = tanhf(scoreg[gid]);
        float xi[10];
#pragma unroll
        for (int k = 0; k < 10; k++) xi[k] = x1g[(size_t)gid * 10 + k] * tt;
        float as_ = 0.f, ad_ = 0.f;
#pragma unroll
        for (int c = 0; c < NC; c++) {
            float v = 0.f;
#pragma unroll
            for (int k = 0; k < 10; k++) v += xi[k] * wgs[k * NC + c];
            hfeatH[p * NC + c] = v;
            as_ += v * asr[c];
            ad_ += v * adr[c];
        }
        alsH[p] = as_;
        aldH[p] = ad_;
    }
    __syncthreads();
    // two-pass softmax over surviving in-edges + self loop
    float res[NC];
    if (tid < KSEL) {
        int p = tid;
        float aldp = aldH[p];
        float lself = leaky(alsH[p] + aldp);
        float m = lself;
        int rp = rpL[p], rc = rcL[p];
        for (int e = 0; e < rc; e++) {
            int s2 = newLs[csrg[rp + e]];
            if (s2 >= 0) m = fmaxf(m, leaky(alsH[s2] + aldp));
        }
        float wself = expf(lself - m);
        float wsum = wself;
#pragma unroll
        for (int c = 0; c < NC; c++) res[c] = wself * hfeatH[p * NC + c];
        for (int e = 0; e < rc; e++) {
            int s2 = newLs[csrg[rp + e]];
            if (s2 < 0) continue;
            float w = expf(leaky(alsH[s2] + aldp) - m);
            wsum += w;
            const float* hsrc = hfeatH + s2 * NC;
#pragma unroll
            for (int c = 0; c < NC; c++) res[c] += w * hsrc[c];
        }
        float inv = 1.f / wsum;
#pragma unroll
        for (int c = 0; c < NC; c++) res[c] *= inv;
    } else {
#pragma unroll
        for (int c = 0; c < NC; c++) res[c] = 0.f;
    }
    // lane butterfly per channel (no barriers), then fold 8 wave partials
#pragma unroll
    for (int c = 0; c < NC; c++) {
        float v = res[c];
#pragma unroll
        for (int d = 1; d < 64; d <<= 1) v += __shfl_xor(v, d, 64);
        res[c] = v;
    }
    if ((tid & 63) == 0)
#pragma unroll
        for (int c = 0; c < NC; c++) wred[(tid >> 6) * NC + c] = res[c];
    __syncthreads();
    if (tid < NC) {
        float a = 0.f;
#pragma unroll
        for (int w = 0; w < 8; w++) a += wred[w * NC + tid];
        goutg[g * HC + hh * NC + tid] = a + (float)KSEL * bg[hh * NC + tid];
    }
}

// ---------------------------------------------------------------------------
// 6. final MLP + log_softmax
// ---------------------------------------------------------------------------
__global__ __launch_bounds__(64) void k_mlp(const float* __restrict__ gout, const float* __restrict__ Wf1,
                                            const float* __restrict__ bf1, const float* __restrict__ Wf2,
                                            const float* __restrict__ bf2, float* __restrict__ out) {
    int g = threadIdx.x;
    if (g >= G) return;
    float gi[HC];
#pragma unroll
    for (int k = 0; k < HC; k++) gi[k] = gout[g * HC + k];
    float hid[30];
    for (int j = 0; j < 30; j++) {
        float s = bf1[j];
        for (int k = 0; k < HC; k++) s += gi[k] * Wf1[k * 30 + j];
        hid[j] = s > 0.f ? s : 0.f;
    }
    float z[3];
    for (int j = 0; j < 3; j++) {
        float s = bf2[j];
        for (int k = 0; k < 30; k++) s += hid[k] * Wf2[k * 3 + j];
        z[j] = s;
    }
    float m = fmaxf(z[0], fmaxf(z[1], z[2]));
    float lse = logf(expf(z[0] - m) + expf(z[1] - m) + expf(z[2] - m)) + m;
    for (int j = 0; j < 3; j++) out[g * 3 + j] = z[j] - lse;
}

extern "C" void kernel_launch(void* const* d_in, const int* in_sizes, int n_in,
                              void* d_out, int out_size, void* d_ws, size_t ws_size,
                              hipStream_t stream) {
    const float* x     = (const float*)d_in[0];
    const int*   src   = (const int*)d_in[1];
    const int*   dst   = (const int*)d_in[2];
    const float* W1    = (const float*)d_in[4];
    const float* b1    = (const float*)d_in[5];
    const float* Ws    = (const float*)d_in[6];
    const float* bs    = (const float*)d_in[7];
    const float* Wg    = (const float*)d_in[8];
    const float* a_src = (const float*)d_in[9];
    const float* a_dst = (const float*)d_in[10];
    const float* bg    = (const float*)d_in[11];
    const float* Wf1   = (const float*)d_in[12];
    const float* bf1   = (const float*)d_in[13];
    const float* Wf2   = (const float*)d_in[14];
    const float* bf2   = (const float*)d_in[15];
    float* out = (float*)d_out;

    const size_t N = NTOT;
    float* ws = (float*)d_ws;
    float* h1g    = ws;                          // 10N
    float* x1g    = h1g + 10 * N;                // 10N
    float* hsg    = x1g + 10 * N;                // N
    float* dinvg  = hsg + N;                     // N
    float* scoreg = dinvg + N;                   // N
    int* rowptrg  = (int*)(scoreg + N);          // N+1
    int* newidxg  = rowptrg + N + 1;             // N
    int* permg    = newidxg + N;                 // NK
    float* goutg  = (float*)(permg + NK);        // G*HC
    unsigned short* csrg = (unsigned short*)(goutg + G * HC);  // NE ushort

    k_csr<<<G, 512, 0, stream>>>(x, src, dst, W1, h1g, dinvg, rowptrg, csrg);
    k_gcn10<<<NTOT / 256, 256, 0, stream>>>(h1g, dinvg, rowptrg, csrg, b1, Ws, x1g, hsg);
    k_score<<<NTOT / 256, 256, 0, stream>>>(hsg, dinvg, rowptrg, csrg, bs, scoreg);
    k_topk<<<G, 256, 0, stream>>>(scoreg, permg, newidxg);
    k_gat<<<G * NH, 512, 0, stream>>>(x1g, scoreg, permg, newidxg, rowptrg, csrg,
                                      Wg, a_src, a_dst, bg, goutg);
    k_mlp<<<1, 64, 0, stream>>>(goutg, Wf1, bf1, Wf2, bf2, out);
}